// Round 10
// baseline (1181.012 us; speedup 1.0000x reference)
//
#include <hip/hip_runtime.h>
#include <float.h>
#include <stdint.h>

#define IN_DIM 1433
#define HID 16
#define OUTD 7

#define KC 32
#define GROWS 64
#define NT 45                            // ceil(1433/32)
#define KLAST 25                         // 1433 - 44*32

#define AS1 __attribute__((address_space(1)))
#define AS3 __attribute__((address_space(3)))

// ---------------- GEMM1: xw1[N][16] = feat[N][1433] @ W1[1433][16] -------------
// R8 geometry (64 rows/block, KC=32, wave w owns output quad w, XOR-swizzled
// stage verified in R5/R8) + T3/T4 counted-vmcnt pipeline: 3-buffer LDS ring
// (24 KB), steady state keeps 2 tiles in flight per block, s_waitcnt vmcnt(8)
// + raw s_barrier (NEVER vmcnt(0) in the loop). Per-wave stage = exactly 8 DMA
// instrs -> vmcnt counts are uniform; W1 loads are wave-uniform (readfirstlane)
// -> scalar s_load (lgkmcnt), compute is vmcnt-silent.
// Correctness of the wait: each wave's vmcnt(8) BEFORE s_barrier proves its own
// tile-i loads landed; the barrier then makes all waves' loads visible.
__global__ __launch_bounds__(256, 4) void gemm1_kernel(
    const float* __restrict__ feat, const float* __restrict__ W1,
    float* __restrict__ xw1, int N)
{
    __shared__ float xs[3][GROWS * KC];   // 3 * 8 KB
    const int t = threadIdx.x;
    const int lane = t & 63;
    const int w = t >> 6;                 // wave 0..3
    const int row0 = blockIdx.x * GROWS;
    const long maxElem = (long)N * IN_DIM - 1;

    const int r  = t & 63;                // row owned for compute
    const int rb = r & 7;                 // read-side block swizzle key
    const int q4 = __builtin_amdgcn_readfirstlane(w) * 4;  // output quad base

    // precompute the 8 per-instr global offsets (sans k0) and LDS bases
    long ebase[8];
#pragma unroll
    for (int i = 0; i < 8; ++i) {
        const int ri = (i * 4 + w) * 2 + (lane >> 5);
        const int cs = lane & 31;
        const int gcol = (cs & 3) | (((cs >> 2) ^ (ri & 7)) << 2);
        ebase[i] = (long)(row0 + ri) * IN_DIM + gcol;
    }

    float acc[4] = {0.f, 0.f, 0.f, 0.f};

    // stage one 64x32 tile into buf: exactly 8 width-4 DMA instrs per wave
    auto stage = [&](int buf, int k0) {
#pragma unroll
        for (int i = 0; i < 8; ++i) {
            long elem = ebase[i] + k0;
            if (elem > maxElem) elem = maxElem;   // tail clamp (rows >= N only)
            __builtin_amdgcn_global_load_lds(
                (const AS1 void*)(feat + elem),
                (AS3 void*)(&xs[buf][(i * 4 + w) * 64]), 4, 0, 0);
        }
    };

#define COMPUTE(buf, k0v, KMAX)                                              \
    {                                                                        \
        const float* xrow = &xs[buf][r * KC];                                \
        _Pragma("unroll")                                                    \
        for (int b = 0; b < ((KMAX) >> 2); ++b) {                            \
            const float4 xv = *(const float4*)&xrow[((b ^ rb) << 2)];        \
            const float* wk = W1 + (size_t)((k0v) + 4 * b) * HID + q4;       \
            const float4 w0 = *(const float4*)(wk);                          \
            const float4 w1 = *(const float4*)(wk + HID);                    \
            const float4 w2 = *(const float4*)(wk + 2 * HID);                \
            const float4 w3 = *(const float4*)(wk + 3 * HID);                \
            acc[0] += xv.x * w0.x; acc[1] += xv.x * w0.y;                    \
            acc[2] += xv.x * w0.z; acc[3] += xv.x * w0.w;                    \
            acc[0] += xv.y * w1.x; acc[1] += xv.y * w1.y;                    \
            acc[2] += xv.y * w1.z; acc[3] += xv.y * w1.w;                    \
            acc[0] += xv.z * w2.x; acc[1] += xv.z * w2.y;                    \
            acc[2] += xv.z * w2.z; acc[3] += xv.z * w2.w;                    \
            acc[0] += xv.w * w3.x; acc[1] += xv.w * w3.y;                    \
            acc[2] += xv.w * w3.z; acc[3] += xv.w * w3.w;                    \
        }                                                                    \
        if ((KMAX) & 3) {   /* KLAST=25: one remaining k */                  \
            const int b = (KMAX) >> 2;                                       \
            const float4 xv = *(const float4*)&xrow[((b ^ rb) << 2)];        \
            const float* wk = W1 + (size_t)((k0v) + 4 * b) * HID + q4;       \
            const float4 w0 = *(const float4*)(wk);                          \
            acc[0] += xv.x * w0.x; acc[1] += xv.x * w0.y;                    \
            acc[2] += xv.x * w0.z; acc[3] += xv.x * w0.w;                    \
        }                                                                    \
    }

    // wait for own tile-i loads (leave 8 = next tile in flight), then barrier
#define WAITBAR(Nimm)                                                        \
    asm volatile("s_waitcnt vmcnt(" #Nimm ")" ::: "memory");                 \
    __builtin_amdgcn_sched_barrier(0);                                       \
    __builtin_amdgcn_s_barrier();                                            \
    __builtin_amdgcn_sched_barrier(0);

    stage(0, 0);
    stage(1, KC);                         // 16 DMA outstanding
    for (int g = 0; g < 13; ++g) {        // tiles 3g, 3g+1, 3g+2 (0..38)
        const int k0 = g * (3 * KC);
        WAITBAR(8); stage(2, k0 + 2 * KC); COMPUTE(0, k0, KC);
        WAITBAR(8); stage(0, k0 + 3 * KC); COMPUTE(1, k0 + KC, KC);
        WAITBAR(8); stage(1, k0 + 4 * KC); COMPUTE(2, k0 + 2 * KC, KC);
    }
    // tiles 39..44 (stages 41..44)
    WAITBAR(8); stage(2, 41 * KC); COMPUTE(0, 39 * KC, KC);
    WAITBAR(8); stage(0, 42 * KC); COMPUTE(1, 40 * KC, KC);
    WAITBAR(8); stage(1, 43 * KC); COMPUTE(2, 41 * KC, KC);
    WAITBAR(8); stage(2, 44 * KC); COMPUTE(0, 42 * KC, KC);
    WAITBAR(8);                    COMPUTE(1, 43 * KC, KC);
    WAITBAR(0);                    COMPUTE(2, 44 * KC, KLAST);
#undef COMPUTE
#undef WAITBAR

    const int grow = row0 + r;
    if (grow < N)
        *(float4*)(xw1 + (size_t)grow * HID + q4) =
            make_float4(acc[0], acc[1], acc[2], acc[3]);
}

// ---------------- CSR build: histogram -> scan -> counting-sort fill ----------
__global__ __launch_bounds__(256) void hist_kernel(
    const int* __restrict__ dst, int* __restrict__ cnt, int E)
{
    const int e = blockIdx.x * 256 + threadIdx.x;
    if (e < E) atomicAdd(&cnt[dst[e]], 1);
}

__global__ __launch_bounds__(256) void scan1_kernel(
    const int* __restrict__ cnt, int* __restrict__ offs,
    int* __restrict__ bsum, int N)
{
    __shared__ int lds[256];
    const int t = threadIdx.x, b = blockIdx.x;
    const int base = b * 1024 + t * 4;
    int c0 = 0, c1 = 0, c2 = 0, c3 = 0;
    if (base + 0 < N) c0 = cnt[base + 0];
    if (base + 1 < N) c1 = cnt[base + 1];
    if (base + 2 < N) c2 = cnt[base + 2];
    if (base + 3 < N) c3 = cnt[base + 3];
    const int s = c0 + c1 + c2 + c3;
    lds[t] = s;
    __syncthreads();
    for (int off = 1; off < 256; off <<= 1) {
        int v = (t >= off) ? lds[t - off] : 0;
        __syncthreads();
        lds[t] += v;
        __syncthreads();
    }
    const int excl = lds[t] - s;
    if (t == 255) bsum[b] = lds[255];
    int run = excl;
    if (base + 0 < N) { offs[base + 0] = run; run += c0; }
    if (base + 1 < N) { offs[base + 1] = run; run += c1; }
    if (base + 2 < N) { offs[base + 2] = run; run += c2; }
    if (base + 3 < N) { offs[base + 3] = run; run += c3; }
}

__global__ __launch_bounds__(256) void scan2_kernel(
    const int* __restrict__ bsum, int* __restrict__ bbase, int NB)
{
    __shared__ int lds[256];
    const int t = threadIdx.x;
    const int v = (t < NB) ? bsum[t] : 0;
    lds[t] = v;
    __syncthreads();
    for (int off = 1; off < 256; off <<= 1) {
        int u = (t >= off) ? lds[t - off] : 0;
        __syncthreads();
        lds[t] += u;
        __syncthreads();
    }
    bbase[t] = lds[t] - v;
}

__global__ __launch_bounds__(256) void scan3_kernel(
    int* __restrict__ offs, int* __restrict__ cursor,
    const int* __restrict__ bbase, int N, int E)
{
    const int t = threadIdx.x, b = blockIdx.x;
    const int add = bbase[b];
    const int base = b * 1024 + t * 4;
#pragma unroll
    for (int i = 0; i < 4; ++i) {
        const int idx = base + i;
        if (idx < N) {
            const int v = offs[idx] + add;
            offs[idx] = v;
            cursor[idx] = v;
        }
    }
    if (b == 0 && t == 0) offs[N] = E;
}

__global__ __launch_bounds__(256) void fill_kernel(
    const int* __restrict__ src, const int* __restrict__ dst,
    const float* __restrict__ a, int* __restrict__ cursor,
    uint2* __restrict__ pairs, int E)
{
    const int e = blockIdx.x * 256 + threadIdx.x;
    if (e >= E) return;
    const int d = dst[e];
    const int pos = atomicAdd(&cursor[d], 1);
    pairs[pos] = make_uint2((unsigned)src[e], __float_as_uint(a[e]));
}

// ------- gather1: agg = sum(a*xw1[src]) ; fused h=relu(agg+b1); xw2 = h@W2 ----
__global__ __launch_bounds__(256) void gather1_kernel(
    const uint2* __restrict__ pairs, const int* __restrict__ offs,
    const float* __restrict__ xw1, const float* __restrict__ b1,
    const float* __restrict__ W2, float* __restrict__ xw2, int N)
{
    __shared__ float w2s[HID * OUTD];
    const int t = threadIdx.x;
    if (t < HID * OUTD) w2s[t] = W2[t];
    __syncthreads();
    const int lane = t & 63;
    const int r = blockIdx.x * 4 + (t >> 6);
    if (r >= N) return;
    const int g = lane >> 2;
    const int c = lane & 3;
    const int start = offs[r], end = offs[r + 1];
    float4 acc = make_float4(0.f, 0.f, 0.f, 0.f);
    int e = start + g;
    for (; e + 16 < end; e += 32) {
        const uint2 p0 = pairs[e];
        const uint2 p1 = pairs[e + 16];
        const float4 v0 = *(const float4*)(xw1 + (size_t)p0.x * HID + c * 4);
        const float4 v1 = *(const float4*)(xw1 + (size_t)p1.x * HID + c * 4);
        const float a0 = __uint_as_float(p0.y);
        const float a1 = __uint_as_float(p1.y);
        acc.x += a0 * v0.x + a1 * v1.x;
        acc.y += a0 * v0.y + a1 * v1.y;
        acc.z += a0 * v0.z + a1 * v1.z;
        acc.w += a0 * v0.w + a1 * v1.w;
    }
    if (e < end) {
        const uint2 p0 = pairs[e];
        const float4 v0 = *(const float4*)(xw1 + (size_t)p0.x * HID + c * 4);
        const float a0 = __uint_as_float(p0.y);
        acc.x += a0 * v0.x; acc.y += a0 * v0.y;
        acc.z += a0 * v0.z; acc.w += a0 * v0.w;
    }
#pragma unroll
    for (int m = 4; m < 64; m <<= 1) {
        acc.x += __shfl_xor(acc.x, m);
        acc.y += __shfl_xor(acc.y, m);
        acc.z += __shfl_xor(acc.z, m);
        acc.w += __shfl_xor(acc.w, m);
    }
    const float4 b1v = ((const float4*)b1)[c];
    float4 hv;
    hv.x = fmaxf(acc.x + b1v.x, 0.f);
    hv.y = fmaxf(acc.y + b1v.y, 0.f);
    hv.z = fmaxf(acc.z + b1v.z, 0.f);
    hv.w = fmaxf(acc.w + b1v.w, 0.f);
    float hh[16];
#pragma unroll
    for (int cc = 0; cc < 4; ++cc) {
        hh[cc * 4 + 0] = __shfl(hv.x, cc);
        hh[cc * 4 + 1] = __shfl(hv.y, cc);
        hh[cc * 4 + 2] = __shfl(hv.z, cc);
        hh[cc * 4 + 3] = __shfl(hv.w, cc);
    }
    const int col = (lane & 7) < OUTD ? (lane & 7) : 0;
    float sacc = 0.f;
#pragma unroll
    for (int j = 0; j < HID; ++j) sacc += hh[j] * w2s[j * OUTD + col];
    if (lane < 8) xw2[(size_t)r * 8 + lane] = (lane < OUTD) ? sacc : 0.f;
}

// ------- gather2: o = sum(a*xw2[src]) + b2 ; fused log_softmax -> out ---------
__global__ __launch_bounds__(256) void gather2_kernel(
    const uint2* __restrict__ pairs, const int* __restrict__ offs,
    const float* __restrict__ xw2, const float* __restrict__ b2,
    float* __restrict__ out, int N)
{
    const int t = threadIdx.x;
    const int lane = t & 63;
    const int r = blockIdx.x * 4 + (t >> 6);
    if (r >= N) return;
    const int g = lane >> 1;
    const int c = lane & 1;
    const int start = offs[r], end = offs[r + 1];
    float4 acc = make_float4(0.f, 0.f, 0.f, 0.f);
    for (int e = start + g; e < end; e += 32) {
        const uint2 p = pairs[e];
        const float4 v = *(const float4*)(xw2 + (size_t)p.x * 8 + c * 4);
        const float a = __uint_as_float(p.y);
        acc.x += a * v.x; acc.y += a * v.y;
        acc.z += a * v.z; acc.w += a * v.w;
    }
#pragma unroll
    for (int m = 2; m < 64; m <<= 1) {
        acc.x += __shfl_xor(acc.x, m);
        acc.y += __shfl_xor(acc.y, m);
        acc.z += __shfl_xor(acc.z, m);
        acc.w += __shfl_xor(acc.w, m);
    }
    float4 x;
    if (c == 0) {
        const float4 b2v = *(const float4*)b2;
        x.x = acc.x + b2v.x; x.y = acc.y + b2v.y;
        x.z = acc.z + b2v.z; x.w = acc.w + b2v.w;
    } else {
        x.x = acc.x + b2[4]; x.y = acc.y + b2[5];
        x.z = acc.z + b2[6]; x.w = -FLT_MAX;
    }
    float mymax = fmaxf(fmaxf(x.x, x.y), x.z);
    if (c == 0) mymax = fmaxf(mymax, x.w);
    const float m = fmaxf(mymax, __shfl_xor(mymax, 1));
    float es = expf(x.x - m) + expf(x.y - m) + expf(x.z - m);
    if (c == 0) es += expf(x.w - m);
    const float s = es + __shfl_xor(es, 1);
    const float lg = logf(s);
    float* op = out + (size_t)r * OUTD;
    if (c == 0) {
        op[0] = x.x - m - lg; op[1] = x.y - m - lg;
        op[2] = x.z - m - lg; op[3] = x.w - m - lg;
    } else {
        op[4] = x.x - m - lg; op[5] = x.y - m - lg;
        op[6] = x.z - m - lg;
    }
}

extern "C" void kernel_launch(void* const* d_in, const int* in_sizes, int n_in,
                              void* d_out, int out_size, void* d_ws, size_t ws_size,
                              hipStream_t stream)
{
    const float* feat  = (const float*)d_in[0];
    const int*   esrc  = (const int*)d_in[1];
    const int*   edst  = (const int*)d_in[2];
    const float* avals = (const float*)d_in[3];
    const float* W1    = (const float*)d_in[4];
    const float* b1    = (const float*)d_in[5];
    const float* W2    = (const float*)d_in[6];
    const float* b2    = (const float*)d_in[7];
    float* out = (float*)d_out;

    const int N = in_sizes[0] / IN_DIM;   // 150000
    const int E = in_sizes[1];            // 4800000
    const int NB = (N + 1023) / 1024;     // 147 (<=256 for scan2)

    // workspace layout
    char* p = (char*)d_ws;
    float* xw1   = (float*)p; p += (size_t)N * HID * sizeof(float);
    float* xw2   = (float*)p; p += (size_t)N * 8 * sizeof(float);
    int*   cnt   = (int*)p;   p += (size_t)N * sizeof(int);
    int*   offs  = (int*)p;   p += (size_t)(N + 1) * sizeof(int);
    int*   cursor= (int*)p;   p += (size_t)N * sizeof(int);
    int*   bsum  = (int*)p;   p += 256 * sizeof(int);
    int*   bbase = (int*)p;   p += 256 * sizeof(int);
    p = (char*)(((uintptr_t)p + 15) & ~(uintptr_t)15);
    uint2* pairs = (uint2*)p;

    hipMemsetAsync(cnt, 0, (size_t)N * sizeof(int), stream);

    gemm1_kernel<<<(N + GROWS - 1) / GROWS, 256, 0, stream>>>(feat, W1, xw1, N);

    hist_kernel<<<(E + 255) / 256, 256, 0, stream>>>(edst, cnt, E);
    scan1_kernel<<<NB, 256, 0, stream>>>(cnt, offs, bsum, N);
    scan2_kernel<<<1, 256, 0, stream>>>(bsum, bbase, NB);
    scan3_kernel<<<NB, 256, 0, stream>>>(offs, cursor, bbase, N, E);
    fill_kernel<<<(E + 255) / 256, 256, 0, stream>>>(esrc, edst, avals, cursor, pairs, E);

    gather1_kernel<<<(N + 3) / 4, 256, 0, stream>>>(pairs, offs, xw1, b1, W2, xw2, N);
    gather2_kernel<<<(N + 3) / 4, 256, 0, stream>>>(pairs, offs, xw2, b2, out, N);
}

// Round 11
// 1117.082 us; speedup vs baseline: 1.0572x; 1.0572x over previous
//
#include <hip/hip_runtime.h>
#include <float.h>
#include <stdint.h>

#define IN_DIM 1433
#define HID 16
#define OUTD 7

#define KC 32
#define NT 45                            // ceil(1433/32)
// last tile: 25 k's = 6 float4-blocks + 1 scalar

#define AS1 __attribute__((address_space(1)))
#define AS3 __attribute__((address_space(3)))

// ---------------- GEMM1: xw1[N][16] = feat[N][1433] @ W1[1433][16] -------------
// Barrier-free per-wave pipeline: each wave owns 64 rows (lane = row) and
// computes ALL 16 outputs (acc[16]) -> W1[k][0..15] is wave-uniform (s_load,
// vmcnt-silent) and LDS is wave-private -> NO __syncthreads anywhere.
// Ring-2 LDS buffers per wave (2 x 8 KB); tile i+1's 32 DMA instrs issue before
// computing tile i; per-wave s_waitcnt vmcnt(32) = "my tile-i data landed".
// 16 KB permanently in flight per wave (~73 KB/CU at 9 waves/CU).
// Stage pattern byte-identical to R8: instr = 2 rows x 128 B, XOR-pre-swizzled
// global source (rule #21); read of f4-block b at physical b^(r&7).
__global__ __launch_bounds__(128, 2) void gemm1_kernel(
    const float* __restrict__ feat, const float* __restrict__ W1,
    float* __restrict__ xw1, int N)
{
    __shared__ float xs[2][2][64 * KC];   // [wave][buf] = 4 * 8 KB
    const int t = threadIdx.x;
    const int lane = t & 63;
    const int w = t >> 6;                 // wave 0..1
    const int row0 = blockIdx.x * 128 + w * 64;   // this wave's row base
    const int l5 = lane >> 5;
    const int cs = lane & 31;
    const long maxElem = (long)N * IN_DIM - 1;

    // per-lane swizzled col for instr parity m = i&3 (row of instr i = 2i+l5)
    int co[4];
#pragma unroll
    for (int m = 0; m < 4; ++m)
        co[m] = (cs & 3) | (((cs >> 2) ^ ((2 * m + l5) & 7)) << 2);

    const long A = (long)(row0 + l5) * IN_DIM;

    // stage one 64x32 tile: 32 width-4 DMA instrs (2 rows x 128 B each)
    auto stage = [&](int buf, int k0) {
#pragma unroll
        for (int i = 0; i < 32; ++i) {
            long elem = A + (long)(2 * i) * IN_DIM + k0 + co[i & 3];
            if (elem > maxElem) elem = maxElem;   // tail clamp (rows >= N)
            __builtin_amdgcn_global_load_lds(
                (const AS1 void*)(feat + elem),
                (AS3 void*)(&xs[w][buf][(2 * i) * KC]), 4, 0, 0);
        }
    };

    const int r  = lane;                  // row owned for compute
    const int rb = r & 7;
    float acc[16];
#pragma unroll
    for (int j = 0; j < 16; ++j) acc[j] = 0.f;

#define COMPUTE(buf, k0v, NB4, TAIL)                                         \
    {                                                                        \
        const float* xrow = &xs[w][buf][r * KC];                             \
        _Pragma("unroll")                                                    \
        for (int b = 0; b < (NB4); ++b) {                                    \
            const float4 xv = *(const float4*)&xrow[((b ^ rb) << 2)];        \
            const float* wk = W1 + (size_t)((k0v) + 4 * b) * HID;            \
            _Pragma("unroll")                                                \
            for (int e = 0; e < 4; ++e) {                                    \
                const float xe = ((const float*)&xv)[e];                     \
                const float4 wA = *(const float4*)(wk + e * HID);            \
                const float4 wB = *(const float4*)(wk + e * HID + 4);        \
                const float4 wC = *(const float4*)(wk + e * HID + 8);        \
                const float4 wD = *(const float4*)(wk + e * HID + 12);       \
                acc[0]  += xe * wA.x; acc[1]  += xe * wA.y;                  \
                acc[2]  += xe * wA.z; acc[3]  += xe * wA.w;                  \
                acc[4]  += xe * wB.x; acc[5]  += xe * wB.y;                  \
                acc[6]  += xe * wB.z; acc[7]  += xe * wB.w;                  \
                acc[8]  += xe * wC.x; acc[9]  += xe * wC.y;                  \
                acc[10] += xe * wC.z; acc[11] += xe * wC.w;                  \
                acc[12] += xe * wD.x; acc[13] += xe * wD.y;                  \
                acc[14] += xe * wD.z; acc[15] += xe * wD.w;                  \
            }                                                                \
        }                                                                    \
        if (TAIL) {   /* k = k0v + 24 (block 6, elem 0) */                   \
            const float4 xv = *(const float4*)&xrow[((6 ^ rb) << 2)];        \
            const float xe = xv.x;                                           \
            const float* wk = W1 + (size_t)((k0v) + 24) * HID;               \
            const float4 wA = *(const float4*)(wk);                          \
            const float4 wB = *(const float4*)(wk + 4);                      \
            const float4 wC = *(const float4*)(wk + 8);                      \
            const float4 wD = *(const float4*)(wk + 12);                     \
            acc[0]  += xe * wA.x; acc[1]  += xe * wA.y;                      \
            acc[2]  += xe * wA.z; acc[3]  += xe * wA.w;                      \
            acc[4]  += xe * wB.x; acc[5]  += xe * wB.y;                      \
            acc[6]  += xe * wB.z; acc[7]  += xe * wB.w;                      \
            acc[8]  += xe * wC.x; acc[9]  += xe * wC.y;                      \
            acc[10] += xe * wC.z; acc[11] += xe * wC.w;                      \
            acc[12] += xe * wD.x; acc[13] += xe * wD.y;                      \
            acc[14] += xe * wD.z; acc[15] += xe * wD.w;                      \
        }                                                                    \
    }

    // own-wave wait: 32 newest DMAs (next tile) may remain in flight
#define WAITVM(Nimm)                                                         \
    asm volatile("s_waitcnt vmcnt(" #Nimm ")" ::: "memory");                 \
    __builtin_amdgcn_sched_barrier(0);

    stage(0, 0);
    for (int g = 0; g < 22; ++g) {          // tiles 2g, 2g+1 (0..43)
        stage(1, (2 * g + 1) * KC);
        WAITVM(32);
        COMPUTE(0, 2 * g * KC, 8, false);
        stage(0, (2 * g + 2) * KC);         // stages up to tile 44
        WAITVM(32);
        COMPUTE(1, (2 * g + 1) * KC, 8, false);
    }
    WAITVM(0);
    COMPUTE(0, 44 * KC, 6, true);           // tile 44: 25 k's
#undef COMPUTE
#undef WAITVM

    const int grow = row0 + r;
    if (grow < N) {
        float4* o = (float4*)(xw1 + (size_t)grow * HID);
        o[0] = make_float4(acc[0],  acc[1],  acc[2],  acc[3]);
        o[1] = make_float4(acc[4],  acc[5],  acc[6],  acc[7]);
        o[2] = make_float4(acc[8],  acc[9],  acc[10], acc[11]);
        o[3] = make_float4(acc[12], acc[13], acc[14], acc[15]);
    }
}

// ---------------- CSR build: histogram -> scan -> counting-sort fill ----------
__global__ __launch_bounds__(256) void hist_kernel(
    const int* __restrict__ dst, int* __restrict__ cnt, int E)
{
    const int e = blockIdx.x * 256 + threadIdx.x;
    if (e < E) atomicAdd(&cnt[dst[e]], 1);
}

__global__ __launch_bounds__(256) void scan1_kernel(
    const int* __restrict__ cnt, int* __restrict__ offs,
    int* __restrict__ bsum, int N)
{
    __shared__ int lds[256];
    const int t = threadIdx.x, b = blockIdx.x;
    const int base = b * 1024 + t * 4;
    int c0 = 0, c1 = 0, c2 = 0, c3 = 0;
    if (base + 0 < N) c0 = cnt[base + 0];
    if (base + 1 < N) c1 = cnt[base + 1];
    if (base + 2 < N) c2 = cnt[base + 2];
    if (base + 3 < N) c3 = cnt[base + 3];
    const int s = c0 + c1 + c2 + c3;
    lds[t] = s;
    __syncthreads();
    for (int off = 1; off < 256; off <<= 1) {
        int v = (t >= off) ? lds[t - off] : 0;
        __syncthreads();
        lds[t] += v;
        __syncthreads();
    }
    const int excl = lds[t] - s;
    if (t == 255) bsum[b] = lds[255];
    int run = excl;
    if (base + 0 < N) { offs[base + 0] = run; run += c0; }
    if (base + 1 < N) { offs[base + 1] = run; run += c1; }
    if (base + 2 < N) { offs[base + 2] = run; run += c2; }
    if (base + 3 < N) { offs[base + 3] = run; run += c3; }
}

__global__ __launch_bounds__(256) void scan2_kernel(
    const int* __restrict__ bsum, int* __restrict__ bbase, int NB)
{
    __shared__ int lds[256];
    const int t = threadIdx.x;
    const int v = (t < NB) ? bsum[t] : 0;
    lds[t] = v;
    __syncthreads();
    for (int off = 1; off < 256; off <<= 1) {
        int u = (t >= off) ? lds[t - off] : 0;
        __syncthreads();
        lds[t] += u;
        __syncthreads();
    }
    bbase[t] = lds[t] - v;
}

__global__ __launch_bounds__(256) void scan3_kernel(
    int* __restrict__ offs, int* __restrict__ cursor,
    const int* __restrict__ bbase, int N, int E)
{
    const int t = threadIdx.x, b = blockIdx.x;
    const int add = bbase[b];
    const int base = b * 1024 + t * 4;
#pragma unroll
    for (int i = 0; i < 4; ++i) {
        const int idx = base + i;
        if (idx < N) {
            const int v = offs[idx] + add;
            offs[idx] = v;
            cursor[idx] = v;
        }
    }
    if (b == 0 && t == 0) offs[N] = E;
}

__global__ __launch_bounds__(256) void fill_kernel(
    const int* __restrict__ src, const int* __restrict__ dst,
    const float* __restrict__ a, int* __restrict__ cursor,
    uint2* __restrict__ pairs, int E)
{
    const int e = blockIdx.x * 256 + threadIdx.x;
    if (e >= E) return;
    const int d = dst[e];
    const int pos = atomicAdd(&cursor[d], 1);
    pairs[pos] = make_uint2((unsigned)src[e], __float_as_uint(a[e]));
}

// ------- gather1: agg = sum(a*xw1[src]) ; fused h=relu(agg+b1); xw2 = h@W2 ----
__global__ __launch_bounds__(256) void gather1_kernel(
    const uint2* __restrict__ pairs, const int* __restrict__ offs,
    const float* __restrict__ xw1, const float* __restrict__ b1,
    const float* __restrict__ W2, float* __restrict__ xw2, int N)
{
    __shared__ float w2s[HID * OUTD];
    const int t = threadIdx.x;
    if (t < HID * OUTD) w2s[t] = W2[t];
    __syncthreads();
    const int lane = t & 63;
    const int r = blockIdx.x * 4 + (t >> 6);
    if (r >= N) return;
    const int g = lane >> 2;
    const int c = lane & 3;
    const int start = offs[r], end = offs[r + 1];
    float4 acc = make_float4(0.f, 0.f, 0.f, 0.f);
    int e = start + g;
    for (; e + 16 < end; e += 32) {
        const uint2 p0 = pairs[e];
        const uint2 p1 = pairs[e + 16];
        const float4 v0 = *(const float4*)(xw1 + (size_t)p0.x * HID + c * 4);
        const float4 v1 = *(const float4*)(xw1 + (size_t)p1.x * HID + c * 4);
        const float a0 = __uint_as_float(p0.y);
        const float a1 = __uint_as_float(p1.y);
        acc.x += a0 * v0.x + a1 * v1.x;
        acc.y += a0 * v0.y + a1 * v1.y;
        acc.z += a0 * v0.z + a1 * v1.z;
        acc.w += a0 * v0.w + a1 * v1.w;
    }
    if (e < end) {
        const uint2 p0 = pairs[e];
        const float4 v0 = *(const float4*)(xw1 + (size_t)p0.x * HID + c * 4);
        const float a0 = __uint_as_float(p0.y);
        acc.x += a0 * v0.x; acc.y += a0 * v0.y;
        acc.z += a0 * v0.z; acc.w += a0 * v0.w;
    }
#pragma unroll
    for (int m = 4; m < 64; m <<= 1) {
        acc.x += __shfl_xor(acc.x, m);
        acc.y += __shfl_xor(acc.y, m);
        acc.z += __shfl_xor(acc.z, m);
        acc.w += __shfl_xor(acc.w, m);
    }
    const float4 b1v = ((const float4*)b1)[c];
    float4 hv;
    hv.x = fmaxf(acc.x + b1v.x, 0.f);
    hv.y = fmaxf(acc.y + b1v.y, 0.f);
    hv.z = fmaxf(acc.z + b1v.z, 0.f);
    hv.w = fmaxf(acc.w + b1v.w, 0.f);
    float hh[16];
#pragma unroll
    for (int cc = 0; cc < 4; ++cc) {
        hh[cc * 4 + 0] = __shfl(hv.x, cc);
        hh[cc * 4 + 1] = __shfl(hv.y, cc);
        hh[cc * 4 + 2] = __shfl(hv.z, cc);
        hh[cc * 4 + 3] = __shfl(hv.w, cc);
    }
    const int col = (lane & 7) < OUTD ? (lane & 7) : 0;
    float sacc = 0.f;
#pragma unroll
    for (int j = 0; j < HID; ++j) sacc += hh[j] * w2s[j * OUTD + col];
    if (lane < 8) xw2[(size_t)r * 8 + lane] = (lane < OUTD) ? sacc : 0.f;
}

// ------- gather2: o = sum(a*xw2[src]) + b2 ; fused log_softmax -> out ---------
__global__ __launch_bounds__(256) void gather2_kernel(
    const uint2* __restrict__ pairs, const int* __restrict__ offs,
    const float* __restrict__ xw2, const float* __restrict__ b2,
    float* __restrict__ out, int N)
{
    const int t = threadIdx.x;
    const int lane = t & 63;
    const int r = blockIdx.x * 4 + (t >> 6);
    if (r >= N) return;
    const int g = lane >> 1;
    const int c = lane & 1;
    const int start = offs[r], end = offs[r + 1];
    float4 acc = make_float4(0.f, 0.f, 0.f, 0.f);
    for (int e = start + g; e < end; e += 32) {
        const uint2 p = pairs[e];
        const float4 v = *(const float4*)(xw2 + (size_t)p.x * 8 + c * 4);
        const float a = __uint_as_float(p.y);
        acc.x += a * v.x; acc.y += a * v.y;
        acc.z += a * v.z; acc.w += a * v.w;
    }
#pragma unroll
    for (int m = 2; m < 64; m <<= 1) {
        acc.x += __shfl_xor(acc.x, m);
        acc.y += __shfl_xor(acc.y, m);
        acc.z += __shfl_xor(acc.z, m);
        acc.w += __shfl_xor(acc.w, m);
    }
    float4 x;
    if (c == 0) {
        const float4 b2v = *(const float4*)b2;
        x.x = acc.x + b2v.x; x.y = acc.y + b2v.y;
        x.z = acc.z + b2v.z; x.w = acc.w + b2v.w;
    } else {
        x.x = acc.x + b2[4]; x.y = acc.y + b2[5];
        x.z = acc.z + b2[6]; x.w = -FLT_MAX;
    }
    float mymax = fmaxf(fmaxf(x.x, x.y), x.z);
    if (c == 0) mymax = fmaxf(mymax, x.w);
    const float m = fmaxf(mymax, __shfl_xor(mymax, 1));
    float es = expf(x.x - m) + expf(x.y - m) + expf(x.z - m);
    if (c == 0) es += expf(x.w - m);
    const float s = es + __shfl_xor(es, 1);
    const float lg = logf(s);
    float* op = out + (size_t)r * OUTD;
    if (c == 0) {
        op[0] = x.x - m - lg; op[1] = x.y - m - lg;
        op[2] = x.z - m - lg; op[3] = x.w - m - lg;
    } else {
        op[4] = x.x - m - lg; op[5] = x.y - m - lg;
        op[6] = x.z - m - lg;
    }
}

extern "C" void kernel_launch(void* const* d_in, const int* in_sizes, int n_in,
                              void* d_out, int out_size, void* d_ws, size_t ws_size,
                              hipStream_t stream)
{
    const float* feat  = (const float*)d_in[0];
    const int*   esrc  = (const int*)d_in[1];
    const int*   edst  = (const int*)d_in[2];
    const float* avals = (const float*)d_in[3];
    const float* W1    = (const float*)d_in[4];
    const float* b1    = (const float*)d_in[5];
    const float* W2    = (const float*)d_in[6];
    const float* b2    = (const float*)d_in[7];
    float* out = (float*)d_out;

    const int N = in_sizes[0] / IN_DIM;   // 150000
    const int E = in_sizes[1];            // 4800000
    const int NB = (N + 1023) / 1024;     // 147 (<=256 for scan2)

    // workspace layout
    char* p = (char*)d_ws;
    float* xw1   = (float*)p; p += (size_t)N * HID * sizeof(float);
    float* xw2   = (float*)p; p += (size_t)N * 8 * sizeof(float);
    int*   cnt   = (int*)p;   p += (size_t)N * sizeof(int);
    int*   offs  = (int*)p;   p += (size_t)(N + 1) * sizeof(int);
    int*   cursor= (int*)p;   p += (size_t)N * sizeof(int);
    int*   bsum  = (int*)p;   p += 256 * sizeof(int);
    int*   bbase = (int*)p;   p += 256 * sizeof(int);
    p = (char*)(((uintptr_t)p + 15) & ~(uintptr_t)15);
    uint2* pairs = (uint2*)p;

    hipMemsetAsync(cnt, 0, (size_t)N * sizeof(int), stream);

    gemm1_kernel<<<(N + 127) / 128, 128, 0, stream>>>(feat, W1, xw1, N);

    hist_kernel<<<(E + 255) / 256, 256, 0, stream>>>(edst, cnt, E);
    scan1_kernel<<<NB, 256, 0, stream>>>(cnt, offs, bsum, N);
    scan2_kernel<<<1, 256, 0, stream>>>(bsum, bbase, NB);
    scan3_kernel<<<NB, 256, 0, stream>>>(offs, cursor, bbase, N, E);
    fill_kernel<<<(E + 255) / 256, 256, 0, stream>>>(esrc, edst, avals, cursor, pairs, E);

    gather1_kernel<<<(N + 3) / 4, 256, 0, stream>>>(pairs, offs, xw1, b1, W2, xw2, N);
    gather2_kernel<<<(N + 3) / 4, 256, 0, stream>>>(pairs, offs, xw2, b2, out, N);
}

// Round 12
// 1001.289 us; speedup vs baseline: 1.1795x; 1.1156x over previous
//
#include <hip/hip_runtime.h>
#include <float.h>
#include <stdint.h>

#define IN_DIM 1433
#define HID 16
#define OUTD 7

#define KC 32
#define GROWS 64
#define NT 45                            // ceil(1433/32)
#define KLAST 25                         // 1433 - 44*32

#define AS1 __attribute__((address_space(1)))
#define AS3 __attribute__((address_space(3)))

// ---------------- GEMM1: xw1[N][16] = feat[N][1433] @ W1[1433][16] -------------
// R8 structure restored verbatim (best measured: ~345 us, 2.5 TB/s effective).
// 64 rows/block, 16 KB LDS, (256,8) -> 8 blocks/CU: block-level TLP is the
// empirically best latency-hiding mechanism for this strided-panel pattern
// (beat counted-vmcnt rings, barrier-free per-wave pipelines, width-16 DMA,
// and register streaming across R2-R11).
__global__ __launch_bounds__(256, 8) void gemm1_kernel(
    const float* __restrict__ feat, const float* __restrict__ W1,
    float* __restrict__ xw1, int N)
{
    __shared__ float xs[2][GROWS * KC];   // 2 * 8 KB
    const int t = threadIdx.x;
    const int lane = t & 63;
    const int w = t >> 6;                 // wave 0..3
    const int row0 = blockIdx.x * GROWS;
    const long maxElem = (long)N * IN_DIM - 1;

    const int r  = t & 63;                // row owned for compute
    const int rb = r & 7;                 // read-side block swizzle key
    const int q4 = __builtin_amdgcn_readfirstlane(w) * 4;  // output quad base

    float acc[4] = {0.f, 0.f, 0.f, 0.f};

    // stage one 64x32 tile: 8 width-4 DMA instrs per wave (2 rows x 32 cols each)
    auto stage = [&](int buf, int k0) {
#pragma unroll
        for (int i = 0; i < 8; ++i) {
            const int ri = (i * 4 + w) * 2 + (lane >> 5);
            const int cs = lane & 31;
            const int gcol = (cs & 3) | (((cs >> 2) ^ (ri & 7)) << 2);
            long elem = (long)(row0 + ri) * IN_DIM + k0 + gcol;
            if (elem > maxElem) elem = maxElem;   // tail clamp (unused rows)
            __builtin_amdgcn_global_load_lds(
                (const AS1 void*)(feat + elem),
                (AS3 void*)(&xs[buf][(i * 4 + w) * 64]), 4, 0, 0);
        }
    };

#define COMPUTE(buf, k0v, KMAX)                                              \
    {                                                                        \
        const float* xrow = &xs[buf][r * KC];                                \
        _Pragma("unroll")                                                    \
        for (int b = 0; b < ((KMAX) >> 2); ++b) {                            \
            const float4 xv = *(const float4*)&xrow[((b ^ rb) << 2)];        \
            const float* wk = W1 + (size_t)((k0v) + 4 * b) * HID + q4;       \
            const float4 w0 = *(const float4*)(wk);                          \
            const float4 w1 = *(const float4*)(wk + HID);                    \
            const float4 w2 = *(const float4*)(wk + 2 * HID);                \
            const float4 w3 = *(const float4*)(wk + 3 * HID);                \
            acc[0] += xv.x * w0.x; acc[1] += xv.x * w0.y;                    \
            acc[2] += xv.x * w0.z; acc[3] += xv.x * w0.w;                    \
            acc[0] += xv.y * w1.x; acc[1] += xv.y * w1.y;                    \
            acc[2] += xv.y * w1.z; acc[3] += xv.y * w1.w;                    \
            acc[0] += xv.z * w2.x; acc[1] += xv.z * w2.y;                    \
            acc[2] += xv.z * w2.z; acc[3] += xv.z * w2.w;                    \
            acc[0] += xv.w * w3.x; acc[1] += xv.w * w3.y;                    \
            acc[2] += xv.w * w3.z; acc[3] += xv.w * w3.w;                    \
        }                                                                    \
        if ((KMAX) & 3) {   /* KLAST=25: one remaining k */                  \
            const int b = (KMAX) >> 2;                                       \
            const float4 xv = *(const float4*)&xrow[((b ^ rb) << 2)];        \
            const float* wk = W1 + (size_t)((k0v) + 4 * b) * HID + q4;       \
            const float4 w0 = *(const float4*)(wk);                          \
            acc[0] += xv.x * w0.x; acc[1] += xv.x * w0.y;                    \
            acc[2] += xv.x * w0.z; acc[3] += xv.x * w0.w;                    \
        }                                                                    \
    }

    stage(0, 0);
    __syncthreads();   // tile 0 resident
    for (int it = 0; it < NT - 1; ++it) {
        stage((it & 1) ^ 1, (it + 1) * KC);   // async prefetch next tile
        COMPUTE(it & 1, it * KC, KC);         // compute current tile
        __syncthreads();                      // drain prefetch + buf reuse
    }
    COMPUTE((NT - 1) & 1, (NT - 1) * KC, KLAST);
#undef COMPUTE

    const int grow = row0 + r;
    if (grow < N)
        *(float4*)(xw1 + (size_t)grow * HID + q4) =
            make_float4(acc[0], acc[1], acc[2], acc[3]);
}

// ---------------- CSR build: histogram -> scan -> counting-sort fill ----------
// 4 edges/thread, int4 index loads (E is a multiple of 4; guarded otherwise)
__global__ __launch_bounds__(256) void hist_kernel(
    const int* __restrict__ dst, int* __restrict__ cnt, int E)
{
    const int i4 = blockIdx.x * 256 + threadIdx.x;
    const int e0 = i4 * 4;
    if (e0 + 3 < E) {
        const int4 d = ((const int4*)dst)[i4];
        atomicAdd(&cnt[d.x], 1);
        atomicAdd(&cnt[d.y], 1);
        atomicAdd(&cnt[d.z], 1);
        atomicAdd(&cnt[d.w], 1);
    } else {
        for (int e = e0; e < E; ++e) atomicAdd(&cnt[dst[e]], 1);
    }
}

__global__ __launch_bounds__(256) void scan1_kernel(
    const int* __restrict__ cnt, int* __restrict__ offs,
    int* __restrict__ bsum, int N)
{
    __shared__ int lds[256];
    const int t = threadIdx.x, b = blockIdx.x;
    const int base = b * 1024 + t * 4;
    int c0 = 0, c1 = 0, c2 = 0, c3 = 0;
    if (base + 0 < N) c0 = cnt[base + 0];
    if (base + 1 < N) c1 = cnt[base + 1];
    if (base + 2 < N) c2 = cnt[base + 2];
    if (base + 3 < N) c3 = cnt[base + 3];
    const int s = c0 + c1 + c2 + c3;
    lds[t] = s;
    __syncthreads();
    for (int off = 1; off < 256; off <<= 1) {
        int v = (t >= off) ? lds[t - off] : 0;
        __syncthreads();
        lds[t] += v;
        __syncthreads();
    }
    const int excl = lds[t] - s;
    if (t == 255) bsum[b] = lds[255];
    int run = excl;
    if (base + 0 < N) { offs[base + 0] = run; run += c0; }
    if (base + 1 < N) { offs[base + 1] = run; run += c1; }
    if (base + 2 < N) { offs[base + 2] = run; run += c2; }
    if (base + 3 < N) { offs[base + 3] = run; run += c3; }
}

__global__ __launch_bounds__(256) void scan2_kernel(
    const int* __restrict__ bsum, int* __restrict__ bbase, int NB)
{
    __shared__ int lds[256];
    const int t = threadIdx.x;
    const int v = (t < NB) ? bsum[t] : 0;
    lds[t] = v;
    __syncthreads();
    for (int off = 1; off < 256; off <<= 1) {
        int u = (t >= off) ? lds[t - off] : 0;
        __syncthreads();
        lds[t] += u;
        __syncthreads();
    }
    bbase[t] = lds[t] - v;
}

__global__ __launch_bounds__(256) void scan3_kernel(
    int* __restrict__ offs, int* __restrict__ cursor,
    const int* __restrict__ bbase, int N, int E)
{
    const int t = threadIdx.x, b = blockIdx.x;
    const int add = bbase[b];
    const int base = b * 1024 + t * 4;
#pragma unroll
    for (int i = 0; i < 4; ++i) {
        const int idx = base + i;
        if (idx < N) {
            const int v = offs[idx] + add;
            offs[idx] = v;
            cursor[idx] = v;
        }
    }
    if (b == 0 && t == 0) offs[N] = E;
}

// 4 edges/thread, vectorized reads of src/dst/avals
__global__ __launch_bounds__(256) void fill_kernel(
    const int* __restrict__ src, const int* __restrict__ dst,
    const float* __restrict__ a, int* __restrict__ cursor,
    uint2* __restrict__ pairs, int E)
{
    const int i4 = blockIdx.x * 256 + threadIdx.x;
    const int e0 = i4 * 4;
    if (e0 + 3 < E) {
        const int4   s4 = ((const int4*)src)[i4];
        const int4   d4 = ((const int4*)dst)[i4];
        const float4 a4 = ((const float4*)a)[i4];
        int p0 = atomicAdd(&cursor[d4.x], 1);
        pairs[p0] = make_uint2((unsigned)s4.x, __float_as_uint(a4.x));
        int p1 = atomicAdd(&cursor[d4.y], 1);
        pairs[p1] = make_uint2((unsigned)s4.y, __float_as_uint(a4.y));
        int p2 = atomicAdd(&cursor[d4.z], 1);
        pairs[p2] = make_uint2((unsigned)s4.z, __float_as_uint(a4.z));
        int p3 = atomicAdd(&cursor[d4.w], 1);
        pairs[p3] = make_uint2((unsigned)s4.w, __float_as_uint(a4.w));
    } else {
        for (int e = e0; e < E; ++e) {
            const int pos = atomicAdd(&cursor[dst[e]], 1);
            pairs[pos] = make_uint2((unsigned)src[e], __float_as_uint(a[e]));
        }
    }
}

// ------- gather1: agg = sum(a*xw1[src]) ; fused h=relu(agg+b1); xw2 = h@W2 ----
__global__ __launch_bounds__(256) void gather1_kernel(
    const uint2* __restrict__ pairs, const int* __restrict__ offs,
    const float* __restrict__ xw1, const float* __restrict__ b1,
    const float* __restrict__ W2, float* __restrict__ xw2, int N)
{
    __shared__ float w2s[HID * OUTD];
    const int t = threadIdx.x;
    if (t < HID * OUTD) w2s[t] = W2[t];
    __syncthreads();
    const int lane = t & 63;
    const int r = blockIdx.x * 4 + (t >> 6);
    if (r >= N) return;
    const int g = lane >> 2;
    const int c = lane & 3;
    const int start = offs[r], end = offs[r + 1];
    float4 acc = make_float4(0.f, 0.f, 0.f, 0.f);
    int e = start + g;
    for (; e + 16 < end; e += 32) {
        const uint2 p0 = pairs[e];
        const uint2 p1 = pairs[e + 16];
        const float4 v0 = *(const float4*)(xw1 + (size_t)p0.x * HID + c * 4);
        const float4 v1 = *(const float4*)(xw1 + (size_t)p1.x * HID + c * 4);
        const float a0 = __uint_as_float(p0.y);
        const float a1 = __uint_as_float(p1.y);
        acc.x += a0 * v0.x + a1 * v1.x;
        acc.y += a0 * v0.y + a1 * v1.y;
        acc.z += a0 * v0.z + a1 * v1.z;
        acc.w += a0 * v0.w + a1 * v1.w;
    }
    if (e < end) {
        const uint2 p0 = pairs[e];
        const float4 v0 = *(const float4*)(xw1 + (size_t)p0.x * HID + c * 4);
        const float a0 = __uint_as_float(p0.y);
        acc.x += a0 * v0.x; acc.y += a0 * v0.y;
        acc.z += a0 * v0.z; acc.w += a0 * v0.w;
    }
#pragma unroll
    for (int m = 4; m < 64; m <<= 1) {
        acc.x += __shfl_xor(acc.x, m);
        acc.y += __shfl_xor(acc.y, m);
        acc.z += __shfl_xor(acc.z, m);
        acc.w += __shfl_xor(acc.w, m);
    }
    const float4 b1v = ((const float4*)b1)[c];
    float4 hv;
    hv.x = fmaxf(acc.x + b1v.x, 0.f);
    hv.y = fmaxf(acc.y + b1v.y, 0.f);
    hv.z = fmaxf(acc.z + b1v.z, 0.f);
    hv.w = fmaxf(acc.w + b1v.w, 0.f);
    float hh[16];
#pragma unroll
    for (int cc = 0; cc < 4; ++cc) {
        hh[cc * 4 + 0] = __shfl(hv.x, cc);
        hh[cc * 4 + 1] = __shfl(hv.y, cc);
        hh[cc * 4 + 2] = __shfl(hv.z, cc);
        hh[cc * 4 + 3] = __shfl(hv.w, cc);
    }
    const int col = (lane & 7) < OUTD ? (lane & 7) : 0;
    float sacc = 0.f;
#pragma unroll
    for (int j = 0; j < HID; ++j) sacc += hh[j] * w2s[j * OUTD + col];
    if (lane < 8) xw2[(size_t)r * 8 + lane] = (lane < OUTD) ? sacc : 0.f;
}

// ------- gather2: o = sum(a*xw2[src]) + b2 ; fused log_softmax -> out ---------
__global__ __launch_bounds__(256) void gather2_kernel(
    const uint2* __restrict__ pairs, const int* __restrict__ offs,
    const float* __restrict__ xw2, const float* __restrict__ b2,
    float* __restrict__ out, int N)
{
    const int t = threadIdx.x;
    const int lane = t & 63;
    const int r = blockIdx.x * 4 + (t >> 6);
    if (r >= N) return;
    const int g = lane >> 1;
    const int c = lane & 1;
    const int start = offs[r], end = offs[r + 1];
    float4 acc = make_float4(0.f, 0.f, 0.f, 0.f);
    for (int e = start + g; e < end; e += 32) {
        const uint2 p = pairs[e];
        const float4 v = *(const float4*)(xw2 + (size_t)p.x * 8 + c * 4);
        const float a = __uint_as_float(p.y);
        acc.x += a * v.x; acc.y += a * v.y;
        acc.z += a * v.z; acc.w += a * v.w;
    }
#pragma unroll
    for (int m = 2; m < 64; m <<= 1) {
        acc.x += __shfl_xor(acc.x, m);
        acc.y += __shfl_xor(acc.y, m);
        acc.z += __shfl_xor(acc.z, m);
        acc.w += __shfl_xor(acc.w, m);
    }
    float4 x;
    if (c == 0) {
        const float4 b2v = *(const float4*)b2;
        x.x = acc.x + b2v.x; x.y = acc.y + b2v.y;
        x.z = acc.z + b2v.z; x.w = acc.w + b2v.w;
    } else {
        x.x = acc.x + b2[4]; x.y = acc.y + b2[5];
        x.z = acc.z + b2[6]; x.w = -FLT_MAX;
    }
    float mymax = fmaxf(fmaxf(x.x, x.y), x.z);
    if (c == 0) mymax = fmaxf(mymax, x.w);
    const float m = fmaxf(mymax, __shfl_xor(mymax, 1));
    float es = expf(x.x - m) + expf(x.y - m) + expf(x.z - m);
    if (c == 0) es += expf(x.w - m);
    const float s = es + __shfl_xor(es, 1);
    const float lg = logf(s);
    float* op = out + (size_t)r * OUTD;
    if (c == 0) {
        op[0] = x.x - m - lg; op[1] = x.y - m - lg;
        op[2] = x.z - m - lg; op[3] = x.w - m - lg;
    } else {
        op[4] = x.x - m - lg; op[5] = x.y - m - lg;
        op[6] = x.z - m - lg;
    }
}

extern "C" void kernel_launch(void* const* d_in, const int* in_sizes, int n_in,
                              void* d_out, int out_size, void* d_ws, size_t ws_size,
                              hipStream_t stream)
{
    const float* feat  = (const float*)d_in[0];
    const int*   esrc  = (const int*)d_in[1];
    const int*   edst  = (const int*)d_in[2];
    const float* avals = (const float*)d_in[3];
    const float* W1    = (const float*)d_in[4];
    const float* b1    = (const float*)d_in[5];
    const float* W2    = (const float*)d_in[6];
    const float* b2    = (const float*)d_in[7];
    float* out = (float*)d_out;

    const int N = in_sizes[0] / IN_DIM;   // 150000
    const int E = in_sizes[1];            // 4800000
    const int NB = (N + 1023) / 1024;     // 147 (<=256 for scan2)

    // workspace layout
    char* p = (char*)d_ws;
    float* xw1   = (float*)p; p += (size_t)N * HID * sizeof(float);
    float* xw2   = (float*)p; p += (size_t)N * 8 * sizeof(float);
    int*   cnt   = (int*)p;   p += (size_t)N * sizeof(int);
    int*   offs  = (int*)p;   p += (size_t)(N + 1) * sizeof(int);
    int*   cursor= (int*)p;   p += (size_t)N * sizeof(int);
    int*   bsum  = (int*)p;   p += 256 * sizeof(int);
    int*   bbase = (int*)p;   p += 256 * sizeof(int);
    p = (char*)(((uintptr_t)p + 15) & ~(uintptr_t)15);
    uint2* pairs = (uint2*)p;

    hipMemsetAsync(cnt, 0, (size_t)N * sizeof(int), stream);

    gemm1_kernel<<<(N + GROWS - 1) / GROWS, 256, 0, stream>>>(feat, W1, xw1, N);

    {
        const int n4 = (E + 3) / 4;
        hist_kernel<<<(n4 + 255) / 256, 256, 0, stream>>>(edst, cnt, E);
    }
    scan1_kernel<<<NB, 256, 0, stream>>>(cnt, offs, bsum, N);
    scan2_kernel<<<1, 256, 0, stream>>>(bsum, bbase, NB);
    scan3_kernel<<<NB, 256, 0, stream>>>(offs, cursor, bbase, N, E);
    {
        const int n4 = (E + 3) / 4;
        fill_kernel<<<(n4 + 255) / 256, 256, 0, stream>>>(esrc, edst, avals, cursor, pairs, E);
    }

    gather1_kernel<<<(N + 3) / 4, 256, 0, stream>>>(pairs, offs, xw1, b1, W2, xw2, N);
    gather2_kernel<<<(N + 3) / 4, 256, 0, stream>>>(pairs, offs, xw2, b2, out, N);
}

// Round 13
// 953.456 us; speedup vs baseline: 1.2387x; 1.0502x over previous
//
#include <hip/hip_runtime.h>
#include <float.h>
#include <stdint.h>

#define IN_DIM 1433
#define HID 16
#define OUTD 7

#define AS1 __attribute__((address_space(1)))
#define AS3 __attribute__((address_space(3)))

// ---------------- GEMM1: xw1[N][16] = feat[N][1433] @ W1[1433][16] -------------
// Aligned width-16 DMA gemm. Block = 256 rows; wave w owns the 64 rows
// R = row0 + 4*rc + w (R mod 4 == w), so the row alignment phase
// h = (-w)&3 is WAVE-UNIFORM: every row's k-window [h + 16*i, ...) starts
// 16B-aligned (R*1433 + h == 0 mod 4) -> every global_load_lds width-16 is a
// single aligned line request per lane (the m13/fill request profile), vs the
// 4B-per-lane DMA of R2-R12 (4x the requests -> the 2.5 TB/s ceiling).
// Head k<h done scalar in prologue. Wave-private 2x4KB LDS ring, NO barriers;
// per-wave s_waitcnt vmcnt(4) keeps 1-2 tiles (4-8KB) in flight per wave.
// DMA instr j stages rows rc=16j..16j+15 (64B each, 16 lines, each line
// touched exactly once). LDS: [rc][16 floats], physical slot p of row rc
// holds logical block p^(rc&3) (pre-swizzled source); read block b of row l
// at slot b^(l&3) -> 4-way residual bank aliasing (negligible).
__global__ __launch_bounds__(256, 4) void gemm1_kernel(
    const float* __restrict__ feat, const float* __restrict__ W1,
    float* __restrict__ xw1, int N)
{
    __shared__ float xs[4][2][64 * 16];   // [wave][buf][row][16] = 32 KB
    const int t = threadIdx.x;
    const int l = t & 63;                 // lane = row-within-class
    const int w = t >> 6;                 // wave = residue class
    const int row0 = blockIdx.x * 256;
    const int h = __builtin_amdgcn_readfirstlane((4 - w) & 3);
    const long maxBase = (long)N * IN_DIM - 4;

    const int R = row0 + 4 * l + w;       // compute/output row of this thread

    // per-lane source bases for the 4 DMA instrs of a tile
    long src[4];
#pragma unroll
    for (int j = 0; j < 4; ++j) {
        const int rc = j * 16 + (l >> 2);           // row staged by this lane
        const int bs = (l & 3) ^ (rc & 3);          // pre-swizzled 16B block
        src[j] = (long)(row0 + 4 * rc + w) * IN_DIM + h + 4 * bs;
    }

    float acc[16];
#pragma unroll
    for (int j = 0; j < 16; ++j) acc[j] = 0.f;

    // head: k = 0..h-1 (<=3 scalar elements before the aligned window)
    for (int k = 0; k < h; ++k) {
        const float x = (R < N) ? feat[(long)R * IN_DIM + k] : 0.f;
        const float* wr = W1 + k * HID;
#pragma unroll
        for (int j = 0; j < 16; ++j) acc[j] += x * wr[j];
    }
    asm volatile("s_waitcnt vmcnt(0)" ::: "memory");   // drain head loads
    __builtin_amdgcn_sched_barrier(0);

    // stage tile i (16 k's x 64 rows = 4KB): 4 width-16 DMA instrs
    auto stage = [&](int buf, int i) {
#pragma unroll
        for (int j = 0; j < 4; ++j) {
            long e = src[j] + 16 * i;
            if (e > maxBase) e = maxBase;   // tail clamp (OOB rows / last tile)
            __builtin_amdgcn_global_load_lds(
                (const AS1 void*)(feat + e),
                (AS3 void*)(&xs[w][buf][j * 256]), 16, 0, 0);
        }
    };

#define WAITVM(Nimm)                                                         \
    asm volatile("s_waitcnt vmcnt(" #Nimm ")" ::: "memory");                 \
    __builtin_amdgcn_sched_barrier(0);

    const int lx = l & 3;
    // full tile compute: 4 float4-blocks = 16 k's
#define COMPUTE_FULL(buf, i)                                                 \
    {                                                                        \
        const float* xrow = &xs[w][buf][l * 16];                             \
        const int kb0 = h + 16 * (i);                                        \
        _Pragma("unroll")                                                    \
        for (int b = 0; b < 4; ++b) {                                        \
            const float4 xv = *(const float4*)&xrow[((b ^ lx) << 2)];        \
            const float* wk = W1 + (size_t)(kb0 + 4 * b) * HID;              \
            _Pragma("unroll")                                                \
            for (int e = 0; e < 4; ++e) {                                    \
                const float xe = ((const float*)&xv)[e];                     \
                const float4 wA = *(const float4*)(wk + e * HID);            \
                const float4 wB = *(const float4*)(wk + e * HID + 4);        \
                const float4 wC = *(const float4*)(wk + e * HID + 8);        \
                const float4 wD = *(const float4*)(wk + e * HID + 12);       \
                acc[0]  += xe * wA.x; acc[1]  += xe * wA.y;                  \
                acc[2]  += xe * wA.z; acc[3]  += xe * wA.w;                  \
                acc[4]  += xe * wB.x; acc[5]  += xe * wB.y;                  \
                acc[6]  += xe * wB.z; acc[7]  += xe * wB.w;                  \
                acc[8]  += xe * wC.x; acc[9]  += xe * wC.y;                  \
                acc[10] += xe * wC.z; acc[11] += xe * wC.w;                  \
                acc[12] += xe * wD.x; acc[13] += xe * wD.y;                  \
                acc[14] += xe * wD.z; acc[15] += xe * wD.w;                  \
            }                                                                \
        }                                                                    \
    }

    // 90 tiles cover k = h .. 1432 (head covered 0..h-1); last tile kl = 9-h
    stage(0, 0);
    stage(1, 1);
    for (int i = 0; i < 88; ++i) {
        WAITVM(4);                     // tile i resident; tile i+1 in flight
        COMPUTE_FULL(i & 1, i);
        stage(i & 1, i + 2);           // reuse buf after compute read it
    }
    WAITVM(4);
    COMPUTE_FULL(0, 88);
    WAITVM(0);
    {   // tile 89: kl = 9-h valid k's (wave-uniform)
        const int kl = 9 - h;
        const int nb = kl >> 2, tl = kl & 3;
        const float* xrow = &xs[w][1][l * 16];
        const int kb0 = h + 16 * 89;
        for (int b = 0; b < nb; ++b) {
            const float4 xv = *(const float4*)&xrow[((b ^ lx) << 2)];
            const float* wk = W1 + (size_t)(kb0 + 4 * b) * HID;
#pragma unroll
            for (int e = 0; e < 4; ++e) {
                const float xe = ((const float*)&xv)[e];
                const float* wr = wk + e * HID;
#pragma unroll
                for (int j = 0; j < 16; ++j) acc[j] += xe * wr[j];
            }
        }
        for (int kk = nb * 4; kk < nb * 4 + tl; ++kk) {
            const float x = xrow[(((kk >> 2) ^ lx) << 2) | (kk & 3)];
            const float* wr = W1 + (size_t)(kb0 + kk) * HID;
#pragma unroll
            for (int j = 0; j < 16; ++j) acc[j] += x * wr[j];
        }
    }
#undef COMPUTE_FULL
#undef WAITVM

    if (R < N) {
        float4* o = (float4*)(xw1 + (size_t)R * HID);
        o[0] = make_float4(acc[0],  acc[1],  acc[2],  acc[3]);
        o[1] = make_float4(acc[4],  acc[5],  acc[6],  acc[7]);
        o[2] = make_float4(acc[8],  acc[9],  acc[10], acc[11]);
        o[3] = make_float4(acc[12], acc[13], acc[14], acc[15]);
    }
}

// ---------------- CSR build: histogram -> scan -> counting-sort fill ----------
__global__ __launch_bounds__(256) void hist_kernel(
    const int* __restrict__ dst, int* __restrict__ cnt, int E)
{
    const int i4 = blockIdx.x * 256 + threadIdx.x;
    const int e0 = i4 * 4;
    if (e0 + 3 < E) {
        const int4 d = ((const int4*)dst)[i4];
        atomicAdd(&cnt[d.x], 1);
        atomicAdd(&cnt[d.y], 1);
        atomicAdd(&cnt[d.z], 1);
        atomicAdd(&cnt[d.w], 1);
    } else {
        for (int e = e0; e < E; ++e) atomicAdd(&cnt[dst[e]], 1);
    }
}

__global__ __launch_bounds__(256) void scan1_kernel(
    const int* __restrict__ cnt, int* __restrict__ offs,
    int* __restrict__ bsum, int N)
{
    __shared__ int lds[256];
    const int t = threadIdx.x, b = blockIdx.x;
    const int base = b * 1024 + t * 4;
    int c0 = 0, c1 = 0, c2 = 0, c3 = 0;
    if (base + 0 < N) c0 = cnt[base + 0];
    if (base + 1 < N) c1 = cnt[base + 1];
    if (base + 2 < N) c2 = cnt[base + 2];
    if (base + 3 < N) c3 = cnt[base + 3];
    const int s = c0 + c1 + c2 + c3;
    lds[t] = s;
    __syncthreads();
    for (int off = 1; off < 256; off <<= 1) {
        int v = (t >= off) ? lds[t - off] : 0;
        __syncthreads();
        lds[t] += v;
        __syncthreads();
    }
    const int excl = lds[t] - s;
    if (t == 255) bsum[b] = lds[255];
    int run = excl;
    if (base + 0 < N) { offs[base + 0] = run; run += c0; }
    if (base + 1 < N) { offs[base + 1] = run; run += c1; }
    if (base + 2 < N) { offs[base + 2] = run; run += c2; }
    if (base + 3 < N) { offs[base + 3] = run; run += c3; }
}

__global__ __launch_bounds__(256) void scan2_kernel(
    const int* __restrict__ bsum, int* __restrict__ bbase, int NB)
{
    __shared__ int lds[256];
    const int t = threadIdx.x;
    const int v = (t < NB) ? bsum[t] : 0;
    lds[t] = v;
    __syncthreads();
    for (int off = 1; off < 256; off <<= 1) {
        int u = (t >= off) ? lds[t - off] : 0;
        __syncthreads();
        lds[t] += u;
        __syncthreads();
    }
    bbase[t] = lds[t] - v;
}

__global__ __launch_bounds__(256) void scan3_kernel(
    int* __restrict__ offs, int* __restrict__ cursor,
    const int* __restrict__ bbase, int N, int E)
{
    const int t = threadIdx.x, b = blockIdx.x;
    const int add = bbase[b];
    const int base = b * 1024 + t * 4;
#pragma unroll
    for (int i = 0; i < 4; ++i) {
        const int idx = base + i;
        if (idx < N) {
            const int v = offs[idx] + add;
            offs[idx] = v;
            cursor[idx] = v;
        }
    }
    if (b == 0 && t == 0) offs[N] = E;
}

__global__ __launch_bounds__(256) void fill_kernel(
    const int* __restrict__ src, const int* __restrict__ dst,
    const float* __restrict__ a, int* __restrict__ cursor,
    uint2* __restrict__ pairs, int E)
{
    const int i4 = blockIdx.x * 256 + threadIdx.x;
    const int e0 = i4 * 4;
    if (e0 + 3 < E) {
        const int4   s4 = ((const int4*)src)[i4];
        const int4   d4 = ((const int4*)dst)[i4];
        const float4 a4 = ((const float4*)a)[i4];
        int p0 = atomicAdd(&cursor[d4.x], 1);
        pairs[p0] = make_uint2((unsigned)s4.x, __float_as_uint(a4.x));
        int p1 = atomicAdd(&cursor[d4.y], 1);
        pairs[p1] = make_uint2((unsigned)s4.y, __float_as_uint(a4.y));
        int p2 = atomicAdd(&cursor[d4.z], 1);
        pairs[p2] = make_uint2((unsigned)s4.z, __float_as_uint(a4.z));
        int p3 = atomicAdd(&cursor[d4.w], 1);
        pairs[p3] = make_uint2((unsigned)s4.w, __float_as_uint(a4.w));
    } else {
        for (int e = e0; e < E; ++e) {
            const int pos = atomicAdd(&cursor[dst[e]], 1);
            pairs[pos] = make_uint2((unsigned)src[e], __float_as_uint(a[e]));
        }
    }
}

// ------- gather1: agg = sum(a*xw1[src]) ; fused h=relu(agg+b1); xw2 = h@W2 ----
__global__ __launch_bounds__(256) void gather1_kernel(
    const uint2* __restrict__ pairs, const int* __restrict__ offs,
    const float* __restrict__ xw1, const float* __restrict__ b1,
    const float* __restrict__ W2, float* __restrict__ xw2, int N)
{
    __shared__ float w2s[HID * OUTD];
    const int t = threadIdx.x;
    if (t < HID * OUTD) w2s[t] = W2[t];
    __syncthreads();
    const int lane = t & 63;
    const int r = blockIdx.x * 4 + (t >> 6);
    if (r >= N) return;
    const int g = lane >> 2;
    const int c = lane & 3;
    const int start = offs[r], end = offs[r + 1];
    float4 acc = make_float4(0.f, 0.f, 0.f, 0.f);
    int e = start + g;
    for (; e + 16 < end; e += 32) {
        const uint2 p0 = pairs[e];
        const uint2 p1 = pairs[e + 16];
        const float4 v0 = *(const float4*)(xw1 + (size_t)p0.x * HID + c * 4);
        const float4 v1 = *(const float4*)(xw1 + (size_t)p1.x * HID + c * 4);
        const float a0 = __uint_as_float(p0.y);
        const float a1 = __uint_as_float(p1.y);
        acc.x += a0 * v0.x + a1 * v1.x;
        acc.y += a0 * v0.y + a1 * v1.y;
        acc.z += a0 * v0.z + a1 * v1.z;
        acc.w += a0 * v0.w + a1 * v1.w;
    }
    if (e < end) {
        const uint2 p0 = pairs[e];
        const float4 v0 = *(const float4*)(xw1 + (size_t)p0.x * HID + c * 4);
        const float a0 = __uint_as_float(p0.y);
        acc.x += a0 * v0.x; acc.y += a0 * v0.y;
        acc.z += a0 * v0.z; acc.w += a0 * v0.w;
    }
#pragma unroll
    for (int m = 4; m < 64; m <<= 1) {
        acc.x += __shfl_xor(acc.x, m);
        acc.y += __shfl_xor(acc.y, m);
        acc.z += __shfl_xor(acc.z, m);
        acc.w += __shfl_xor(acc.w, m);
    }
    const float4 b1v = ((const float4*)b1)[c];
    float4 hv;
    hv.x = fmaxf(acc.x + b1v.x, 0.f);
    hv.y = fmaxf(acc.y + b1v.y, 0.f);
    hv.z = fmaxf(acc.z + b1v.z, 0.f);
    hv.w = fmaxf(acc.w + b1v.w, 0.f);
    float hh[16];
#pragma unroll
    for (int cc = 0; cc < 4; ++cc) {
        hh[cc * 4 + 0] = __shfl(hv.x, cc);
        hh[cc * 4 + 1] = __shfl(hv.y, cc);
        hh[cc * 4 + 2] = __shfl(hv.z, cc);
        hh[cc * 4 + 3] = __shfl(hv.w, cc);
    }
    const int col = (lane & 7) < OUTD ? (lane & 7) : 0;
    float sacc = 0.f;
#pragma unroll
    for (int j = 0; j < HID; ++j) sacc += hh[j] * w2s[j * OUTD + col];
    if (lane < 8) xw2[(size_t)r * 8 + lane] = (lane < OUTD) ? sacc : 0.f;
}

// ------- gather2: o = sum(a*xw2[src]) + b2 ; fused log_softmax -> out ---------
__global__ __launch_bounds__(256) void gather2_kernel(
    const uint2* __restrict__ pairs, const int* __restrict__ offs,
    const float* __restrict__ xw2, const float* __restrict__ b2,
    float* __restrict__ out, int N)
{
    const int t = threadIdx.x;
    const int lane = t & 63;
    const int r = blockIdx.x * 4 + (t >> 6);
    if (r >= N) return;
    const int g = lane >> 1;
    const int c = lane & 1;
    const int start = offs[r], end = offs[r + 1];
    float4 acc = make_float4(0.f, 0.f, 0.f, 0.f);
    for (int e = start + g; e < end; e += 32) {
        const uint2 p = pairs[e];
        const float4 v = *(const float4*)(xw2 + (size_t)p.x * 8 + c * 4);
        const float a = __uint_as_float(p.y);
        acc.x += a * v.x; acc.y += a * v.y;
        acc.z += a * v.z; acc.w += a * v.w;
    }
#pragma unroll
    for (int m = 2; m < 64; m <<= 1) {
        acc.x += __shfl_xor(acc.x, m);
        acc.y += __shfl_xor(acc.y, m);
        acc.z += __shfl_xor(acc.z, m);
        acc.w += __shfl_xor(acc.w, m);
    }
    float4 x;
    if (c == 0) {
        const float4 b2v = *(const float4*)b2;
        x.x = acc.x + b2v.x; x.y = acc.y + b2v.y;
        x.z = acc.z + b2v.z; x.w = acc.w + b2v.w;
    } else {
        x.x = acc.x + b2[4]; x.y = acc.y + b2[5];
        x.z = acc.z + b2[6]; x.w = -FLT_MAX;
    }
    float mymax = fmaxf(fmaxf(x.x, x.y), x.z);
    if (c == 0) mymax = fmaxf(mymax, x.w);
    const float m = fmaxf(mymax, __shfl_xor(mymax, 1));
    float es = expf(x.x - m) + expf(x.y - m) + expf(x.z - m);
    if (c == 0) es += expf(x.w - m);
    const float s = es + __shfl_xor(es, 1);
    const float lg = logf(s);
    float* op = out + (size_t)r * OUTD;
    if (c == 0) {
        op[0] = x.x - m - lg; op[1] = x.y - m - lg;
        op[2] = x.z - m - lg; op[3] = x.w - m - lg;
    } else {
        op[4] = x.x - m - lg; op[5] = x.y - m - lg;
        op[6] = x.z - m - lg;
    }
}

extern "C" void kernel_launch(void* const* d_in, const int* in_sizes, int n_in,
                              void* d_out, int out_size, void* d_ws, size_t ws_size,
                              hipStream_t stream)
{
    const float* feat  = (const float*)d_in[0];
    const int*   esrc  = (const int*)d_in[1];
    const int*   edst  = (const int*)d_in[2];
    const float* avals = (const float*)d_in[3];
    const float* W1    = (const float*)d_in[4];
    const float* b1    = (const float*)d_in[5];
    const float* W2    = (const float*)d_in[6];
    const float* b2    = (const float*)d_in[7];
    float* out = (float*)d_out;

    const int N = in_sizes[0] / IN_DIM;   // 150000
    const int E = in_sizes[1];            // 4800000
    const int NB = (N + 1023) / 1024;     // 147 (<=256 for scan2)

    // workspace layout
    char* p = (char*)d_ws;
    float* xw1   = (float*)p; p += (size_t)N * HID * sizeof(float);
    float* xw2   = (float*)p; p += (size_t)N * 8 * sizeof(float);
    int*   cnt   = (int*)p;   p += (size_t)N * sizeof(int);
    int*   offs  = (int*)p;   p += (size_t)(N + 1) * sizeof(int);
    int*   cursor= (int*)p;   p += (size_t)N * sizeof(int);
    int*   bsum  = (int*)p;   p += 256 * sizeof(int);
    int*   bbase = (int*)p;   p += 256 * sizeof(int);
    p = (char*)(((uintptr_t)p + 15) & ~(uintptr_t)15);
    uint2* pairs = (uint2*)p;

    hipMemsetAsync(cnt, 0, (size_t)N * sizeof(int), stream);

    gemm1_kernel<<<(N + 255) / 256, 256, 0, stream>>>(feat, W1, xw1, N);

    {
        const int n4 = (E + 3) / 4;
        hist_kernel<<<(n4 + 255) / 256, 256, 0, stream>>>(edst, cnt, E);
    }
    scan1_kernel<<<NB, 256, 0, stream>>>(cnt, offs, bsum, N);
    scan2_kernel<<<1, 256, 0, stream>>>(bsum, bbase, NB);
    scan3_kernel<<<NB, 256, 0, stream>>>(offs, cursor, bbase, N, E);
    {
        const int n4 = (E + 3) / 4;
        fill_kernel<<<(n4 + 255) / 256, 256, 0, stream>>>(esrc, edst, avals, cursor, pairs, E);
    }

    gather1_kernel<<<(N + 3) / 4, 256, 0, stream>>>(pairs, offs, xw1, b1, W2, xw2, N);
    gather2_kernel<<<(N + 3) / 4, 256, 0, stream>>>(pairs, offs, xw2, b2, out, N);
}